// Round 3
// baseline (47.847 us; speedup 1.0000x reference)
//
#include <hip/hip_runtime.h>

// Problem constants (from reference): B=4, S=2000, F=128, NGRAMS=5, G=400, H=5, K=2
#define BB 4
#define SS 2000
#define FF 128
#define NG 5
#define GG 400
#define HH 5
#define KK 2

#define LOG2E   1.4426950408889634f
#define RSQRT2  0.70710678118654752f

#if defined(__has_builtin)
#if __has_builtin(__builtin_amdgcn_exp2f)
#define EXP2F(x) __builtin_amdgcn_exp2f(x)
#else
#define EXP2F(x) exp2f(x)
#endif
#else
#define EXP2F(x) exp2f(x)
#endif

// One block per (b, g). 320 threads = 5 waves; wave id = head h; lane = token f (+64).
__global__ __launch_bounds__(320) void ngram_mha_kernel(
    const float* __restrict__ x,
    const float* __restrict__ Wq, const float* __restrict__ bq,
    const float* __restrict__ Wk, const float* __restrict__ bk,
    const float* __restrict__ Wv, const float* __restrict__ bv,
    const float* __restrict__ Wo, const float* __restrict__ bo,
    float* __restrict__ out)
{
    const int g   = blockIdx.x;   // 0..399
    const int b   = blockIdx.y;   // 0..3
    const int tid = threadIdx.x;  // 0..319

    // Per-group weights staged in LDS
    __shared__ float wq[50], wk[50], wv[50], wo[50];
    __shared__ float bqs[10], bks[10], bvs[10], bos[5];
    // q (pre-scaled), interleaved k/v, and normalized o
    __shared__ float2 qs[FF * HH];   // qs[f*5+h] = (q0,q1) * (1/sqrt(2))*log2(e)
    __shared__ float4 kv[FF * HH];   // kv[t*5+h] = (k0,k1,v0,v1)
    __shared__ float2 ob[FF * HH];   // ob[f*5+h] = (o0,o1)/sum

    // ---- Phase A: stage weights (uniform, L2-cached; 235 floats) ----
    if      (tid < 50)  wq[tid]       = Wq[g*50 + tid];
    else if (tid < 100) wk[tid - 50]  = Wk[g*50 + (tid - 50)];
    else if (tid < 150) wv[tid - 100] = Wv[g*50 + (tid - 100)];
    else if (tid < 200) wo[tid - 150] = Wo[g*50 + (tid - 150)];
    else if (tid < 210) bqs[tid - 200] = bq[g*10 + (tid - 200)];
    else if (tid < 220) bks[tid - 210] = bk[g*10 + (tid - 210)];
    else if (tid < 230) bvs[tid - 220] = bv[g*10 + (tid - 220)];
    else if (tid < 235) bos[tid - 230] = bo[g*5  + (tid - 230)];

    // ---- Phase B prefetch: h[f,n] = x[b, g*5+n, f] (coalesced in f) ----
    float hx[NG];
    if (tid < FF) {
        const float* xp = x + ((size_t)b * SS + (size_t)g * NG) * FF + tid;
        #pragma unroll
        for (int n = 0; n < NG; ++n) hx[n] = xp[n * FF];
    }
    __syncthreads();

    // ---- Phase B: q/k/v projections (threads 0..127, f = tid) ----
    if (tid < FF) {
        const int f = tid;
        const float cs = RSQRT2 * LOG2E;   // fold score scale + log2(e) into q
        #pragma unroll
        for (int h = 0; h < HH; ++h) {
            float q0 = bqs[h*2 + 0], q1 = bqs[h*2 + 1];
            float k0 = bks[h*2 + 0], k1 = bks[h*2 + 1];
            float v0 = bvs[h*2 + 0], v1 = bvs[h*2 + 1];
            #pragma unroll
            for (int n = 0; n < NG; ++n) {
                const float hv = hx[n];
                q0 = fmaf(hv, wq[(n*5 + h)*2 + 0], q0);
                q1 = fmaf(hv, wq[(n*5 + h)*2 + 1], q1);
                k0 = fmaf(hv, wk[(n*5 + h)*2 + 0], k0);
                k1 = fmaf(hv, wk[(n*5 + h)*2 + 1], k1);
                v0 = fmaf(hv, wv[(n*5 + h)*2 + 0], v0);
                v1 = fmaf(hv, wv[(n*5 + h)*2 + 1], v1);
            }
            qs[f*5 + h] = make_float2(q0 * cs, q1 * cs);
            kv[f*5 + h] = make_float4(k0, k1, v0, v1);
        }
    }
    __syncthreads();

    // ---- Phase C: attention main loop. wave = head, lane handles f=l and f=l+64 ----
    const int h = tid >> 6;   // 0..4
    const int l = tid & 63;
    const float2 qa = qs[l        * 5 + h];
    const float2 qb = qs[(l + 64) * 5 + h];

    float s0 = 0.f, s1 = 0.f;
    float o00 = 0.f, o01 = 0.f, o10 = 0.f, o11 = 0.f;
    const float4* __restrict__ kvh = kv + h;  // kvh[t*5], wave-uniform addr -> LDS broadcast

    #pragma unroll
    for (int t = 0; t < FF; ++t) {
        const float4 e = kvh[t * 5];
        // scores (scale+log2e already folded into q); softmax shift skipped:
        // scores are O(0.1) so exp(s) == exp(s - max) to fp32 rounding.
        const float sa = fmaf(qa.y, e.y, qa.x * e.x);
        const float sb = fmaf(qb.y, e.y, qb.x * e.x);
        const float pa = EXP2F(sa);
        const float pb = EXP2F(sb);
        s0 += pa;  s1 += pb;
        o00 = fmaf(pa, e.z, o00);  o01 = fmaf(pa, e.w, o01);
        o10 = fmaf(pb, e.z, o10);  o11 = fmaf(pb, e.w, o11);
    }
    const float r0 = 1.0f / s0;
    const float r1 = 1.0f / s1;
    ob[l        * 5 + h] = make_float2(o00 * r0, o01 * r0);
    ob[(l + 64) * 5 + h] = make_float2(o10 * r1, o11 * r1);
    __syncthreads();

    // ---- Phase E: output projection + scatter ----
    // out[b,g,f,n] -> d_out[b*256000 + f*2000 + n*400 + g]
    for (int oi = tid; oi < FF * NG; oi += 320) {
        const int f = oi / 5;
        const int n = oi % 5;
        float acc = bos[n];
        #pragma unroll
        for (int hh = 0; hh < HH; ++hh) {
            const float2 o2 = ob[f*5 + hh];
            acc = fmaf(o2.x, wo[(hh*2 + 0)*5 + n], acc);
            acc = fmaf(o2.y, wo[(hh*2 + 1)*5 + n], acc);
        }
        out[(size_t)b * (SS * FF) + (size_t)f * 2000 + n * 400 + g] = acc;
    }
}

extern "C" void kernel_launch(void* const* d_in, const int* in_sizes, int n_in,
                              void* d_out, int out_size, void* d_ws, size_t ws_size,
                              hipStream_t stream) {
    const float* x  = (const float*)d_in[0];
    const float* Wq = (const float*)d_in[1];
    const float* bq = (const float*)d_in[2];
    const float* Wk = (const float*)d_in[3];
    const float* bk = (const float*)d_in[4];
    const float* Wv = (const float*)d_in[5];
    const float* bv = (const float*)d_in[6];
    const float* Wo = (const float*)d_in[7];
    const float* bo = (const float*)d_in[8];
    float* out = (float*)d_out;

    dim3 grid(GG, BB);   // 400 x 4 = 1600 blocks, one per (b,g)
    ngram_mha_kernel<<<grid, 320, 0, stream>>>(x, Wq, bq, Wk, bk, Wv, bv, Wo, bo, out);
}

// Round 4
// 46.316 us; speedup vs baseline: 1.0330x; 1.0330x over previous
//
#include <hip/hip_runtime.h>

// Problem constants: B=4, S=2000, F=128, NGRAMS=5, G=400, H=5, K=2
#define BB 4
#define SS 2000
#define FF 128
#define NG 5
#define GG 400
#define HH 5

#define LOG2E   1.4426950408889634f
#define RSQRT2  0.70710678118654752f

#if defined(__has_builtin)
#if __has_builtin(__builtin_amdgcn_exp2f)
#define EXP2F(x) __builtin_amdgcn_exp2f(x)
#else
#define EXP2F(x) exp2f(x)
#endif
#else
#define EXP2F(x) exp2f(x)
#endif

// Broadcast lane `lane`'s value of v to all lanes (compile-time lane with full unroll).
__device__ __forceinline__ float bcast(float v, int lane) {
    return __int_as_float(__builtin_amdgcn_readlane(__float_as_int(v), lane));
}

// One block per (b, g). 320 threads = 5 waves; wave = head h; lane handles tokens l and l+64.
// Main loop is 100% register-resident: k/v live in 12 VGPRs per lane, per-token
// broadcast via v_readlane (no LDS traffic, no memory latency in the hot loop).
__global__ __launch_bounds__(320) void ngram_mha_kernel(
    const float* __restrict__ x,
    const float* __restrict__ Wq, const float* __restrict__ bq,
    const float* __restrict__ Wk, const float* __restrict__ bk,
    const float* __restrict__ Wv, const float* __restrict__ bv,
    const float* __restrict__ Wo, const float* __restrict__ bo,
    float* __restrict__ out)
{
    const int g   = blockIdx.x;   // 0..399
    const int b   = blockIdx.y;   // 0..3
    const int tid = threadIdx.x;  // 0..319
    const int h   = __builtin_amdgcn_readfirstlane(tid >> 6);  // wave id = head (force SGPR)
    const int l   = tid & 63;

    // LDS only for the cross-head output projection.
    __shared__ float  wo[50];
    __shared__ float  bos[5];
    __shared__ float2 ob[FF * HH];   // ob[f*5+h] = (o0,o1)/sum

    if      (tid < 50) wo[tid]       = Wo[g*50 + tid];
    else if (tid < 55) bos[tid - 50] = bo[g*5 + (tid - 50)];

    // ---- Per-wave weights (wave-uniform addresses -> scalar loads) ----
    float wqh[10], wkh[10], wvh[10];
    #pragma unroll
    for (int n = 0; n < NG; ++n) {
        #pragma unroll
        for (int k = 0; k < 2; ++k) {
            const int wi = g*50 + (n*HH + h)*2 + k;
            wqh[n*2 + k] = Wq[wi];
            wkh[n*2 + k] = Wk[wi];
            wvh[n*2 + k] = Wv[wi];
        }
    }
    const float bq0 = bq[(g*HH + h)*2 + 0], bq1 = bq[(g*HH + h)*2 + 1];
    const float bk0 = bk[(g*HH + h)*2 + 0], bk1 = bk[(g*HH + h)*2 + 1];
    const float bv0 = bv[(g*HH + h)*2 + 0], bv1 = bv[(g*HH + h)*2 + 1];

    // ---- x loads: lane l needs x[b, g*5+n, l] and [.., l+64] (coalesced per wave) ----
    const float* xp = x + ((size_t)b * SS + (size_t)g * NG) * FF;
    float xa[NG], xb[NG];
    #pragma unroll
    for (int n = 0; n < NG; ++n) {
        xa[n] = xp[n * FF + l];
        xb[n] = xp[n * FF + l + 64];
    }

    // ---- q/k/v projection for this wave's head, tokens l (a) and l+64 (b) ----
    float qa0 = bq0, qa1 = bq1, ka0 = bk0, ka1 = bk1, va0 = bv0, va1 = bv1;
    float qb0 = bq0, qb1 = bq1, kb0 = bk0, kb1 = bk1, vb0 = bv0, vb1 = bv1;
    #pragma unroll
    for (int n = 0; n < NG; ++n) {
        const float a = xa[n], c = xb[n];
        qa0 = fmaf(a, wqh[n*2+0], qa0);  qa1 = fmaf(a, wqh[n*2+1], qa1);
        ka0 = fmaf(a, wkh[n*2+0], ka0);  ka1 = fmaf(a, wkh[n*2+1], ka1);
        va0 = fmaf(a, wvh[n*2+0], va0);  va1 = fmaf(a, wvh[n*2+1], va1);
        qb0 = fmaf(c, wqh[n*2+0], qb0);  qb1 = fmaf(c, wqh[n*2+1], qb1);
        kb0 = fmaf(c, wkh[n*2+0], kb0);  kb1 = fmaf(c, wkh[n*2+1], kb1);
        vb0 = fmaf(c, wvh[n*2+0], vb0);  vb1 = fmaf(c, wvh[n*2+1], vb1);
    }
    // Fold score scale (1/sqrt(2)) and log2(e) into q so softmax is a bare exp2.
    const float cs = RSQRT2 * LOG2E;
    qa0 *= cs; qa1 *= cs; qb0 *= cs; qb1 *= cs;

    // ---- Main loop: register-only. Softmax shift skipped (scores ~ O(0.1)). ----
    float s0 = 0.f, s1 = 0.f;
    float o00 = 0.f, o01 = 0.f, o10 = 0.f, o11 = 0.f;
    #pragma unroll
    for (int t = 0; t < FF; ++t) {
        const int lane = t & 63;
        float k0, k1, v0, v1;
        if (t < 64) {
            k0 = bcast(ka0, lane); k1 = bcast(ka1, lane);
            v0 = bcast(va0, lane); v1 = bcast(va1, lane);
        } else {
            k0 = bcast(kb0, lane); k1 = bcast(kb1, lane);
            v0 = bcast(vb0, lane); v1 = bcast(vb1, lane);
        }
        const float sa = fmaf(qa1, k1, qa0 * k0);
        const float sb = fmaf(qb1, k1, qb0 * k0);
        const float pa = EXP2F(sa);
        const float pb = EXP2F(sb);
        s0 += pa;  s1 += pb;
        o00 = fmaf(pa, v0, o00);  o01 = fmaf(pa, v1, o01);
        o10 = fmaf(pb, v0, o10);  o11 = fmaf(pb, v1, o11);
    }
    const float r0 = 1.0f / s0;
    const float r1 = 1.0f / s1;
    ob[l        * HH + h] = make_float2(o00 * r0, o01 * r0);
    ob[(l + 64) * HH + h] = make_float2(o10 * r1, o11 * r1);
    __syncthreads();

    // ---- Output projection + scatter: out[b,g,f,n] -> d_out[b*256000 + f*2000 + n*400 + g] ----
    for (int oi = tid; oi < FF * NG; oi += 320) {
        const int f = oi / 5;
        const int n = oi % 5;
        float acc = bos[n];
        #pragma unroll
        for (int hh = 0; hh < HH; ++hh) {
            const float2 o2 = ob[f*5 + hh];
            acc = fmaf(o2.x, wo[(hh*2 + 0)*5 + n], acc);
            acc = fmaf(o2.y, wo[(hh*2 + 1)*5 + n], acc);
        }
        out[(size_t)b * (SS * FF) + (size_t)f * 2000 + n * 400 + g] = acc;
    }
}

extern "C" void kernel_launch(void* const* d_in, const int* in_sizes, int n_in,
                              void* d_out, int out_size, void* d_ws, size_t ws_size,
                              hipStream_t stream) {
    const float* x  = (const float*)d_in[0];
    const float* Wq = (const float*)d_in[1];
    const float* bq = (const float*)d_in[2];
    const float* Wk = (const float*)d_in[3];
    const float* bk = (const float*)d_in[4];
    const float* Wv = (const float*)d_in[5];
    const float* bv = (const float*)d_in[6];
    const float* Wo = (const float*)d_in[7];
    const float* bo = (const float*)d_in[8];
    float* out = (float*)d_out;

    dim3 grid(GG, BB);   // 1600 blocks, one per (b,g)
    ngram_mha_kernel<<<grid, 320, 0, stream>>>(x, Wq, bq, Wk, bk, Wv, bv, Wo, bo, out);
}